// Round 2
// baseline (194.276 us; speedup 1.0000x reference)
//
#include <hip/hip_runtime.h>
#include <math.h>

typedef short short8 __attribute__((ext_vector_type(8)));
typedef float f32x4 __attribute__((ext_vector_type(4)));

typedef __attribute__((address_space(1))) const void* as1p;
typedef __attribute__((address_space(3))) void* as3p;

__device__ __forceinline__ unsigned short f2bf(float f) {
    unsigned int u = __float_as_uint(f);
    u += 0x7fffu + ((u >> 16) & 1u);          // RNE; inputs finite
    return (unsigned short)(u >> 16);
}
__device__ __forceinline__ float bf2f(unsigned int bits) {
    return __uint_as_float(bits << 16);
}

// ---------------------------------------------------------------------------
// fp32 -> bf16 conversion of x, W_qkv, W_o in one launch (4 elems/thread)
// ---------------------------------------------------------------------------
__global__ void cvt_all_bf16(const float* __restrict__ x,
                             const float* __restrict__ wqkv,
                             const float* __restrict__ wo,
                             unsigned short* __restrict__ xb,
                             unsigned short* __restrict__ wqkvb,
                             unsigned short* __restrict__ wob) {
    int i = blockIdx.x * blockDim.x + threadIdx.x;   // [0, 2097152)
    const float* src;
    unsigned short* dst;
    int off;
    if (i < 1048576)       { src = x;    dst = xb;    off = i; }
    else if (i < 1835008)  { src = wqkv; dst = wqkvb; off = i - 1048576; }
    else                   { src = wo;   dst = wob;   off = i - 1835008; }
    float4 v = ((const float4*)src)[off];
    ushort4 o = make_ushort4(f2bf(v.x), f2bf(v.y), f2bf(v.z), f2bf(v.w));
    ((ushort4*)dst)[off] = o;
}

// ---------------------------------------------------------------------------
// MFMA NT GEMM: C[m,n] = sum_k A[m,k]*B[n,k]. Block tile BM x 128 (BM=RF*32),
// BK=32, 4 waves (2x2), global_load_lds width-16 staging, 2-barrier K-loop.
// LDS bank-conflict fix via global-source XOR swizzle (global_load_lds pins
// the LDS slot to base + lane*16, so the swizzle permutes the source chunk).
// XCD-swizzled flat grid: xcd = L%8 owns NTX consecutive n-tiles (B panel
// L2-resident). DO_ROPE: fused RoPE on the fp32 accumulator before store.
// ---------------------------------------------------------------------------
template <int RF, int NTX, bool BF16_OUT, bool DO_ROPE>
__global__ __launch_bounds__(256) void gemm_nt_mfma(
    const unsigned short* __restrict__ A, const unsigned short* __restrict__ B,
    void* __restrict__ Cv, const int* __restrict__ pos, int N, int K) {
    constexpr int BM = RF * 32;
    __shared__ unsigned short As[BM * 32];
    __shared__ unsigned short Bs[128 * 32];
    const int tid = threadIdx.x;
    const int wave = tid >> 6, lane = tid & 63;
    const int L = blockIdx.x;
    const int xcd = L & 7, idx = L >> 3;
    const int nt_ = xcd * NTX + idx % NTX;
    const int mt  = idx / NTX;
    const int m0 = mt * BM, n0 = nt_ << 7;
    const int wr = ((wave >> 1) & 1) * (RF * 16);
    const int wc = (wave & 1) << 6;

    // staging: slot tid -> row tid>>2, swizzled source chunk
    const int r0 = tid >> 2;
    const int ko = (((tid & 3) ^ ((r0 >> 1) & 3)) << 3);
    const unsigned short* Ap0 = A + (size_t)(m0 + r0) * K + ko;
    const unsigned short* Ap1 = A + (size_t)(m0 + (RF == 4 ? 64 : 0) + r0) * K + ko;
    const unsigned short* Bp0 = B + (size_t)(n0 + r0) * K + ko;
    const unsigned short* Bp1 = B + (size_t)(n0 + 64 + r0) * K + ko;

    f32x4 acc[RF][4] = {};
    const int lro = lane & 15;
    const int cs = ((lane >> 4) ^ ((lro >> 1) & 3)) << 3;  // physical chunk (shorts)

    for (int k0 = 0; k0 < K; k0 += 32) {
        __syncthreads();
        __builtin_amdgcn_global_load_lds((as1p)(Ap0 + k0), (as3p)(As + tid * 8), 16, 0, 0);
        if constexpr (RF == 4)
            __builtin_amdgcn_global_load_lds((as1p)(Ap1 + k0), (as3p)(As + (256 + tid) * 8), 16, 0, 0);
        __builtin_amdgcn_global_load_lds((as1p)(Bp0 + k0), (as3p)(Bs + tid * 8), 16, 0, 0);
        __builtin_amdgcn_global_load_lds((as1p)(Bp1 + k0), (as3p)(Bs + (256 + tid) * 8), 16, 0, 0);
        __syncthreads();

        short8 af[RF], bfr[4];
        #pragma unroll
        for (int i = 0; i < RF; i++) af[i] = *(const short8*)&As[(wr + i * 16 + lro) * 32 + cs];
        #pragma unroll
        for (int j = 0; j < 4; j++) bfr[j] = *(const short8*)&Bs[(wc + j * 16 + lro) * 32 + cs];
        #pragma unroll
        for (int i = 0; i < RF; i++)
            #pragma unroll
            for (int j = 0; j < 4; j++)
                acc[i][j] = __builtin_amdgcn_mfma_f32_16x16x32_bf16(af[i], bfr[j], acc[i][j], 0, 0, 0);
    }

    const int row_b = m0 + wr + ((lane >> 4) << 2);
    const int col_b = n0 + wc + lro;

    if constexpr (DO_ROPE) {
        const int sec = (n0 + wc) >> 10;           // 0=q, 1=k, 2=v
        if (sec < 2) {
            const float qs = (sec == 0) ? 0.18033688011112042f : 1.0f;  // 1/8*log2e
            const float sgn = (lane & 1) ? 1.0f : -1.0f;
            float ps[RF * 4];
            #pragma unroll
            for (int i = 0; i < RF; i++)
                #pragma unroll
                for (int r = 0; r < 4; r++)
                    ps[i * 4 + r] = (float)pos[(row_b + i * 16 + r) & 2047];
            #pragma unroll
            for (int j = 0; j < 4; j++) {
                // inv_freq / (2*pi):  10000^(-fi/32) * 0.159155,  fi = lro/2 + 8j
                float invf_rev = exp2f(-(float)((lro >> 1) + 8 * j) * 0.41524101186092029f)
                                 * 0.15915494309189535f;
                #pragma unroll
                for (int i = 0; i < RF; i++)
                    #pragma unroll
                    for (int r = 0; r < 4; r++) {
                        float rev = ps[i * 4 + r] * invf_rev;
                        rev -= floorf(rev);
                        float c = __builtin_amdgcn_cosf(rev) * qs;
                        float s = __builtin_amdgcn_sinf(rev) * (qs * sgn);
                        float mine = acc[i][j][r];
                        float partner = __shfl_xor(mine, 1, 64);
                        acc[i][j][r] = mine * c + partner * s;
                    }
            }
        }
    }

    #pragma unroll
    for (int i = 0; i < RF; i++)
        #pragma unroll
        for (int j = 0; j < 4; j++)
            #pragma unroll
            for (int r = 0; r < 4; r++) {
                size_t idx2 = (size_t)(row_b + i * 16 + r) * N + (col_b + j * 16);
                if constexpr (BF16_OUT) ((unsigned short*)Cv)[idx2] = f2bf(acc[i][j][r]);
                else ((float*)Cv)[idx2] = acc[i][j][r];
            }
}

// ---------------------------------------------------------------------------
// MFMA causal flash attention — r2: QBLK=128 with 32 q-rows PER WAVE (two
// 16-row fragments). Rationale (r1 post-mortem): kernel is LDS-read-bound
// contributory + latency-bound; each wave reads the FULL 8KB K tile + 8KB V
// tile per iteration, so halving waves-per-q-row halves LDS read traffic per
// unit work (K/V frags loaded once, used by two MFMA row-streams), doubles
// per-wave ILP (two independent accumulator chains), and halves barriers +
// global K/V staging per unit work (8704 block-iters vs 16896).
// Grid: 512 blocks x 256 thr, per-CU PAIRED: blocks L and L+256 land on the
// same CU under the round-robin heuristic; qt pairing (15-m, m) gives every
// CU exactly 34 iterations. XCD-swizzled: 4 (b,h) groups per XCD (K/V
// L2-resident, 2 MB / 4 MiB). Softmax: pre-scaled exp2, no running max,
// denominator reduced once. Per iter ONE barrier; K(kt+1) async
// global_load_lds; V(kt+1) register-prefetch + transpose at iter bottom.
// K LDS 16B-chunk XOR swizzle; V quad-swizzled; P stride 80 (128 rows).
// LDS 55.3 KB -> 2 blocks/CU even if usable pool is 128 KB.
// ---------------------------------------------------------------------------
__global__ __launch_bounds__(256) void flash_attn_mfma(
    const unsigned short* __restrict__ qkv, unsigned short* __restrict__ Ows) {
    const int S = 2048, D3 = 3072;
    const int L = blockIdx.x;                  // [0, 512)
    const int xcd = L & 7;
    const int rr  = (L >> 3) & 31;             // CU slot within XCD
    const int kk  = L >> 8;                    // 0: first 256 blocks, 1: second
    const int qt = kk ? (rr & 15) : (15 - (rr & 15));
    const int g  = (kk << 1) + (rr >> 4);      // 4 (b,h) groups per XCD
    const int g2 = xcd + (g << 3);
    const int h = g2 & 15, b = g2 >> 4;
    const int tid = threadIdx.x, wave = tid >> 6, lane = tid & 63;
    const int lro = lane & 15, grp = lane >> 4;
    const int wb = wave << 5;                  // wave's 32-row base

    __shared__ __align__(16) unsigned short Ks[2][64 * 64];
    __shared__ __align__(16) unsigned int   Vp[2][64 * 36];
    __shared__ __align__(16) unsigned short Ps[128 * 80];

    // staging geometry (K): slot s -> row s>>3, swizzled source chunk
    const int sr = tid >> 3;
    const int sc = ((tid & 7) ^ (sr & 7)) << 3;
    // V transpose geometry
    const int kp = tid >> 3, vo = (tid & 7) << 3;
    const int vka = (kp >> 1) + ((kp & 1) << 5);
    const int vcol = (((kp >> 2) ^ (tid & 7)) << 2) | (kp & 3);

    // frag LDS offsets
    const int cq = grp ^ (lro & 7);
    int kof0[4], kof1[4], vbse[4], vq[4];
    #pragma unroll
    for (int nt = 0; nt < 4; nt++) {
        int R = nt * 16 + lro;
        kof0[nt] = R * 64 + cq * 8;
        kof1[nt] = R * 64 + (cq ^ 4) * 8;
        vbse[nt] = R * 36;
        vq[nt] = (grp ^ (R >> 3)) << 2;
    }
    int apo[2], prowv[2];
    #pragma unroll
    for (int rf = 0; rf < 2; rf++) {
        apo[rf]   = (wb + rf * 16 + lro) * 80 + grp * 8;
        prowv[rf] = wb + rf * 16 + grp * 4;
    }

    const unsigned short* kbg = qkv + (size_t)(b * S) * D3 + 1024 + h * 64;
    const unsigned short* vbg = qkv + (size_t)(b * S) * D3 + 2048 + h * 64;

    const int q0 = qt << 7;
    const int nkt = 2 * qt + 2;

    // Q frags direct from global: rows wb+rf*16+lro, k-halves grp*8 / +32
    short8 aq[2][2];
    #pragma unroll
    for (int rf = 0; rf < 2; rf++) {
        const unsigned short* qrow =
            qkv + (size_t)(b * S + q0 + wb + rf * 16 + lro) * D3 + h * 64 + grp * 8;
        aq[rf][0] = *(const short8*)qrow;
        aq[rf][1] = *(const short8*)(qrow + 32);
    }

    // prime tile 0: K async, V reg->transpose
    __builtin_amdgcn_global_load_lds((as1p)(kbg + (size_t)sr * D3 + sc),
                                     (as3p)&Ks[0][tid * 8], 16, 0, 0);
    __builtin_amdgcn_global_load_lds((as1p)(kbg + (size_t)(sr + 32) * D3 + sc),
                                     (as3p)&Ks[0][(tid + 256) * 8], 16, 0, 0);
    {
        const unsigned short* vs = vbg + (size_t)vka * D3 + vo;
        uint4 va = *(const uint4*)vs;
        uint4 vb = *(const uint4*)(vs + (size_t)16 * D3);
        const unsigned short* pa = (const unsigned short*)&va;
        const unsigned short* pb = (const unsigned short*)&vb;
        #pragma unroll
        for (int j = 0; j < 8; j++)
            Vp[0][(vo + j) * 36 + vcol] = (unsigned)pa[j] | ((unsigned)pb[j] << 16);
    }
    __syncthreads();                       // K0 drained, V0 visible

    f32x4 acc_o[2][4] = {};
    float lsum[2][4] = {};

    for (int kt = 0; kt < nkt; kt++) {
        const int cur = kt & 1, nxt = cur ^ 1;
        const bool pf = (kt + 1 < nkt);
        uint4 va, vb;
        if (pf) {                          // prefetch kt+1 (overlaps compute)
            const unsigned short* kb1 = kbg + (size_t)((kt + 1) * 64) * D3;
            __builtin_amdgcn_global_load_lds((as1p)(kb1 + (size_t)sr * D3 + sc),
                                             (as3p)&Ks[nxt][tid * 8], 16, 0, 0);
            __builtin_amdgcn_global_load_lds((as1p)(kb1 + (size_t)(sr + 32) * D3 + sc),
                                             (as3p)&Ks[nxt][(tid + 256) * 8], 16, 0, 0);
            const unsigned short* vs = vbg + (size_t)((kt + 1) * 64 + vka) * D3 + vo;
            va = *(const uint4*)vs;
            vb = *(const uint4*)(vs + (size_t)16 * D3);
        }

        // S = Q K^T  (pre-scaled so p = exp2(s)); K frags shared by both rf
        f32x4 s[2][4] = {};
        #pragma unroll
        for (int nt = 0; nt < 4; nt++) {
            short8 bk0 = *(const short8*)&Ks[cur][kof0[nt]];
            short8 bk1 = *(const short8*)&Ks[cur][kof1[nt]];
            #pragma unroll
            for (int rf = 0; rf < 2; rf++) {
                s[rf][nt] = __builtin_amdgcn_mfma_f32_16x16x32_bf16(aq[rf][0], bk0, s[rf][nt], 0, 0, 0);
                s[rf][nt] = __builtin_amdgcn_mfma_f32_16x16x32_bf16(aq[rf][1], bk1, s[rf][nt], 0, 0, 0);
            }
        }

        // diagonal spans the last TWO k-tiles at QBLK=128
        const bool dg = (kt >= nkt - 2);
        const int moff = dg ? ((kt - (nkt - 2)) << 6) : 0;   // 0 or 64
        #pragma unroll
        for (int rf = 0; rf < 2; rf++) {
            #pragma unroll
            for (int r = 0; r < 4; r++) {
                float v0 = s[rf][0][r], v1 = s[rf][1][r], v2 = s[rf][2][r], v3 = s[rf][3][r];
                if (dg) {
                    int thr = prowv[rf] + r - moff;
                    if (lro > thr) v0 = -1e30f;
                    if (16 + lro > thr) v1 = -1e30f;
                    if (32 + lro > thr) v2 = -1e30f;
                    if (48 + lro > thr) v3 = -1e30f;
                }
                float p0 = __builtin_amdgcn_exp2f(v0);
                float p1 = __builtin_amdgcn_exp2f(v1);
                float p2 = __builtin_amdgcn_exp2f(v2);
                float p3 = __builtin_amdgcn_exp2f(v3);
                lsum[rf][r] += (p0 + p1) + (p2 + p3);
                // cheap (round-half-up) bf16 pack
                unsigned u0 = __float_as_uint(p0) + 0x8000u;
                unsigned u1 = __float_as_uint(p1) + 0x8000u;
                unsigned u2 = __float_as_uint(p2) + 0x8000u;
                unsigned u3 = __float_as_uint(p3) + 0x8000u;
                uint2 w = make_uint2((u0 >> 16) | (u1 & 0xffff0000u),
                                     (u2 >> 16) | (u3 & 0xffff0000u));
                *(uint2*)&Ps[(prowv[rf] + r) * 80 + lro * 4] = w;
            }
        }

        // O += P V  (same-wave in-order LDS RAW on Ps); V frags shared by both rf
        short8 ap[2][2];
        #pragma unroll
        for (int rf = 0; rf < 2; rf++) {
            ap[rf][0] = *(const short8*)&Ps[apo[rf]];
            ap[rf][1] = *(const short8*)&Ps[apo[rf] + 32];
        }
        #pragma unroll
        for (int nt = 0; nt < 4; nt++) {
            short8 bv0 = *(const short8*)&Vp[cur][vbse[nt] + vq[nt]];
            short8 bv1 = *(const short8*)&Vp[cur][vbse[nt] + (vq[nt] ^ 16)];
            #pragma unroll
            for (int rf = 0; rf < 2; rf++) {
                acc_o[rf][nt] = __builtin_amdgcn_mfma_f32_16x16x32_bf16(ap[rf][0], bv0, acc_o[rf][nt], 0, 0, 0);
                acc_o[rf][nt] = __builtin_amdgcn_mfma_f32_16x16x32_bf16(ap[rf][1], bv1, acc_o[rf][nt], 0, 0, 0);
            }
        }

        if (pf) {                          // transpose-write V(kt+1)
            const unsigned short* pa = (const unsigned short*)&va;
            const unsigned short* pb = (const unsigned short*)&vb;
            #pragma unroll
            for (int j = 0; j < 8; j++)
                Vp[nxt][(vo + j) * 36 + vcol] = (unsigned)pa[j] | ((unsigned)pb[j] << 16);
        }
        __syncthreads();                   // drains async K(kt+1); Vp[nxt] visible
    }

    // epilogue: reduce l across the 16 lanes holding each row, normalize
    #pragma unroll
    for (int rf = 0; rf < 2; rf++) {
        #pragma unroll
        for (int r = 0; r < 4; r++) {
            float rsum = lsum[rf][r];
            #pragma unroll
            for (int off = 1; off < 16; off <<= 1)
                rsum += __shfl_xor(rsum, off, 16);
            float inv = 1.0f / rsum;
            int row = q0 + prowv[rf] + r;
            #pragma unroll
            for (int nt = 0; nt < 4; nt++)
                Ows[(size_t)(b * S + row) * 1024 + h * 64 + nt * 16 + lro] =
                    f2bf(acc_o[rf][nt][r] * inv);
        }
    }
}

// ---------------------------------------------------------------------------
extern "C" void kernel_launch(void* const* d_in, const int* in_sizes, int n_in,
                              void* d_out, int out_size, void* d_ws, size_t ws_size,
                              hipStream_t stream) {
    const float* x    = (const float*)d_in[0];   // (2, 2048, 1024)
    const int*   pos  = (const int*)d_in[1];     // (2048,)
    const float* Wqkv = (const float*)d_in[2];   // (3072, 1024)
    const float* Wo   = (const float*)d_in[3];   // (1024, 1024)
    float* out = (float*)d_out;                  // (2, 2048, 1024) fp32

    unsigned short* xb    = (unsigned short*)d_ws;            // 4096*1024
    unsigned short* Wqkvb = xb + (size_t)4096 * 1024;         // 3072*1024
    unsigned short* Wob   = Wqkvb + (size_t)3072 * 1024;      // 1024*1024
    unsigned short* qkvb  = Wob + (size_t)1024 * 1024;        // 4096*3072
    unsigned short* Owsb  = qkvb + (size_t)4096 * 3072;       // 4096*1024

    // 0) fp32 -> bf16 (single launch)
    cvt_all_bf16<<<8192, 256, 0, stream>>>(x, Wqkv, Wo, xb, Wqkvb, Wob);

    // 1) QKV projection (M=4096, N=3072, K=1024) + fused RoPE, swizzled LDS
    gemm_nt_mfma<4, 3, true, true><<<768, 256, 0, stream>>>(
        xb, Wqkvb, qkvb, pos, 3072, 1024);

    // 2) causal flash attention (QBLK=128, 32 rows/wave, per-CU paired grid)
    flash_attn_mfma<<<512, 256, 0, stream>>>(qkvb, Owsb);

    // 3) output projection (M=4096, N=1024, K=1024), BM=64, swizzled LDS
    gemm_nt_mfma<2, 1, false, false><<<512, 256, 0, stream>>>(
        Owsb, Wob, out, nullptr, 1024, 1024);
}

// Round 3
// 185.035 us; speedup vs baseline: 1.0499x; 1.0499x over previous
//
#include <hip/hip_runtime.h>
#include <math.h>

typedef short short8 __attribute__((ext_vector_type(8)));
typedef float f32x4 __attribute__((ext_vector_type(4)));
typedef unsigned int u32x2 __attribute__((ext_vector_type(2)));

typedef __attribute__((address_space(1))) const void* as1p;
typedef __attribute__((address_space(3))) void* as3p;

__device__ __forceinline__ unsigned short f2bf(float f) {
    unsigned int u = __float_as_uint(f);
    u += 0x7fffu + ((u >> 16) & 1u);          // RNE; inputs finite
    return (unsigned short)(u >> 16);
}

// ---------------------------------------------------------------------------
// fp32 -> bf16 conversion of x, W_qkv, W_o in one launch (4 elems/thread)
// ---------------------------------------------------------------------------
__global__ void cvt_all_bf16(const float* __restrict__ x,
                             const float* __restrict__ wqkv,
                             const float* __restrict__ wo,
                             unsigned short* __restrict__ xb,
                             unsigned short* __restrict__ wqkvb,
                             unsigned short* __restrict__ wob) {
    int i = blockIdx.x * blockDim.x + threadIdx.x;   // [0, 2097152)
    const float* src;
    unsigned short* dst;
    int off;
    if (i < 1048576)       { src = x;    dst = xb;    off = i; }
    else if (i < 1835008)  { src = wqkv; dst = wqkvb; off = i - 1048576; }
    else                   { src = wo;   dst = wob;   off = i - 1835008; }
    float4 v = ((const float4*)src)[off];
    ushort4 o = make_ushort4(f2bf(v.x), f2bf(v.y), f2bf(v.z), f2bf(v.w));
    ((ushort4*)dst)[off] = o;
}

// ---------------------------------------------------------------------------
// MFMA NT GEMM: C[m,n] = sum_k A[m,k]*B[n,k]. Block tile BM x 128 (BM=RF*32),
// BK=32, 4 waves (2x2), global_load_lds width-16 staging, 2-barrier K-loop.
// LDS bank-conflict fix via global-source XOR swizzle. XCD-swizzled flat
// grid. DO_ROPE: fused RoPE on the fp32 accumulator before store.
// ---------------------------------------------------------------------------
template <int RF, int NTX, bool BF16_OUT, bool DO_ROPE>
__global__ __launch_bounds__(256) void gemm_nt_mfma(
    const unsigned short* __restrict__ A, const unsigned short* __restrict__ B,
    void* __restrict__ Cv, const int* __restrict__ pos, int N, int K) {
    constexpr int BM = RF * 32;
    __shared__ unsigned short As[BM * 32];
    __shared__ unsigned short Bs[128 * 32];
    const int tid = threadIdx.x;
    const int wave = tid >> 6, lane = tid & 63;
    const int L = blockIdx.x;
    const int xcd = L & 7, idx = L >> 3;
    const int nt_ = xcd * NTX + idx % NTX;
    const int mt  = idx / NTX;
    const int m0 = mt * BM, n0 = nt_ << 7;
    const int wr = ((wave >> 1) & 1) * (RF * 16);
    const int wc = (wave & 1) << 6;

    const int r0 = tid >> 2;
    const int ko = (((tid & 3) ^ ((r0 >> 1) & 3)) << 3);
    const unsigned short* Ap0 = A + (size_t)(m0 + r0) * K + ko;
    const unsigned short* Ap1 = A + (size_t)(m0 + (RF == 4 ? 64 : 0) + r0) * K + ko;
    const unsigned short* Bp0 = B + (size_t)(n0 + r0) * K + ko;
    const unsigned short* Bp1 = B + (size_t)(n0 + 64 + r0) * K + ko;

    f32x4 acc[RF][4] = {};
    const int lro = lane & 15;
    const int cs = ((lane >> 4) ^ ((lro >> 1) & 3)) << 3;  // physical chunk (shorts)

    for (int k0 = 0; k0 < K; k0 += 32) {
        __syncthreads();
        __builtin_amdgcn_global_load_lds((as1p)(Ap0 + k0), (as3p)(As + tid * 8), 16, 0, 0);
        if constexpr (RF == 4)
            __builtin_amdgcn_global_load_lds((as1p)(Ap1 + k0), (as3p)(As + (256 + tid) * 8), 16, 0, 0);
        __builtin_amdgcn_global_load_lds((as1p)(Bp0 + k0), (as3p)(Bs + tid * 8), 16, 0, 0);
        __builtin_amdgcn_global_load_lds((as1p)(Bp1 + k0), (as3p)(Bs + (256 + tid) * 8), 16, 0, 0);
        __syncthreads();

        short8 af[RF], bfr[4];
        #pragma unroll
        for (int i = 0; i < RF; i++) af[i] = *(const short8*)&As[(wr + i * 16 + lro) * 32 + cs];
        #pragma unroll
        for (int j = 0; j < 4; j++) bfr[j] = *(const short8*)&Bs[(wc + j * 16 + lro) * 32 + cs];
        #pragma unroll
        for (int i = 0; i < RF; i++)
            #pragma unroll
            for (int j = 0; j < 4; j++)
                acc[i][j] = __builtin_amdgcn_mfma_f32_16x16x32_bf16(af[i], bfr[j], acc[i][j], 0, 0, 0);
    }

    const int row_b = m0 + wr + ((lane >> 4) << 2);
    const int col_b = n0 + wc + lro;

    if constexpr (DO_ROPE) {
        const int sec = (n0 + wc) >> 10;           // 0=q, 1=k, 2=v
        if (sec < 2) {
            const float qs = (sec == 0) ? 0.18033688011112042f : 1.0f;  // 1/8*log2e
            const float sgn = (lane & 1) ? 1.0f : -1.0f;
            float ps[RF * 4];
            #pragma unroll
            for (int i = 0; i < RF; i++)
                #pragma unroll
                for (int r = 0; r < 4; r++)
                    ps[i * 4 + r] = (float)pos[(row_b + i * 16 + r) & 2047];
            #pragma unroll
            for (int j = 0; j < 4; j++) {
                float invf_rev = exp2f(-(float)((lro >> 1) + 8 * j) * 0.41524101186092029f)
                                 * 0.15915494309189535f;
                #pragma unroll
                for (int i = 0; i < RF; i++)
                    #pragma unroll
                    for (int r = 0; r < 4; r++) {
                        float rev = ps[i * 4 + r] * invf_rev;
                        rev -= floorf(rev);
                        float c = __builtin_amdgcn_cosf(rev) * qs;
                        float s = __builtin_amdgcn_sinf(rev) * (qs * sgn);
                        float mine = acc[i][j][r];
                        float partner = __shfl_xor(mine, 1, 64);
                        acc[i][j][r] = mine * c + partner * s;
                    }
            }
        }
    }

    #pragma unroll
    for (int i = 0; i < RF; i++)
        #pragma unroll
        for (int j = 0; j < 4; j++)
            #pragma unroll
            for (int r = 0; r < 4; r++) {
                size_t idx2 = (size_t)(row_b + i * 16 + r) * N + (col_b + j * 16);
                if constexpr (BF16_OUT) ((unsigned short*)Cv)[idx2] = f2bf(acc[i][j][r]);
                else ((float*)Cv)[idx2] = acc[i][j][r];
            }
}

// ---------------------------------------------------------------------------
// MFMA causal flash attention — r3: K-SLICED WAVES + SWAPPED QK^T, P in
// registers. r0 grid/pairing kept (dim3(16,16,2), in-block (pp, 31-pp) phase
// pairing = guaranteed 33 iters/block; r2's cross-block pairing failed).
// Each wave owns a 16-row k-slice of the 64-row KV tile and computes
// S^T = mfma(K_slice, Q^T) for ALL 64 q-rows (4 q-frags). Layout identity:
// 16x16x32 D-output (col=q=lane&15, row=k=grp*4+r) == A-operand layout of
// v_mfma_f32_16x16x16_bf16 (row=lane&15, k=grp*4+j), so P feeds PV directly
// from registers: the Ps LDS buffer, its writes, same-wave RAW drain, and
// reads are all deleted. V stored transposed with (k,k+1) uint pairs so the
// 16x16x16 B-frag is one ds_read_b64. LDS traffic per block-iter: 96->32KB.
// Per-wave partial O (its k-slice) reduced across waves once per phase via
// 4 static rounds through RedW (static acc indexing only — rule #20).
// lsum: per-lane partial -> shfl over grp -> Lbuf -> summed by owner.
// ---------------------------------------------------------------------------
__global__ __launch_bounds__(256) void flash_attn_mfma(
    const unsigned short* __restrict__ qkv, unsigned short* __restrict__ Ows) {
    const int S = 2048, D3 = 3072;
    const int L = blockIdx.x + (blockIdx.y << 4) + (blockIdx.z << 8);
    const int xcd = L & 7, t = L >> 3;
    const int pp = t & 15;
    const int g2 = xcd + ((t >> 4) << 3);      // (b,h) group, constant per XCD
    const int h = g2 & 15, b = g2 >> 4;
    const int tid = threadIdx.x, wave = tid >> 6, lane = tid & 63;
    const int lro = lane & 15, grp = lane >> 4;

    __shared__ __align__(16) unsigned short Ks[2][64 * 64];
    __shared__ __align__(16) unsigned int   Vp[2][64 * 34];
    __shared__ float RedW[4][16][66];
    __shared__ float Lbuf[4][4][16];

    // K staging geometry: slot s -> row s>>3, swizzled source chunk
    const int sr = tid >> 3;
    const int sc = ((tid & 7) ^ (sr & 7)) << 3;
    // V transpose geometry: thread handles k-rows (2m, 2m+1), d = vo..vo+7
    const int m = tid >> 3;            // 0..31 (k-pair index)
    const int vo = (tid & 7) << 3;     // 0..56 (d base)

    // K frag offsets (A-operand rows = wave*16 + lro, chunk-swizzled)
    const int Rk = (wave << 4) + lro;
    const int koffA = Rk * 64 + ((grp ^ (lro & 7)) << 3);
    const int koffB = Rk * 64 + (((grp ^ 4) ^ (lro & 7)) << 3);
    // V frag uint-col base: k = wave*16 + grp*4 .. +3  ->  cols (8w+2g, +1)
    const int vcb = (wave << 3) + (grp << 1);
    const int klb = (wave << 4) + (grp << 2);   // lane's k_local base

    const unsigned short* kbg = qkv + (size_t)(b * S) * D3 + 1024 + h * 64;
    const unsigned short* vbg = qkv + (size_t)(b * S) * D3 + 2048 + h * 64;

    for (int ph = 0; ph < 2; ph++) {
        const int qt = ph ? 31 - pp : pp;
        const int q0 = qt << 6;
        const int nkt = qt + 1;

        __syncthreads();                       // prior phase fully done with LDS

        // Q frags (B-operand: col=q=lane&15 within frag f, d-chunk grp*8/+32)
        short8 bq[4][2];
        #pragma unroll
        for (int f = 0; f < 4; f++) {
            const unsigned short* qrow =
                qkv + (size_t)(b * S + q0 + f * 16 + lro) * D3 + h * 64 + grp * 8;
            bq[f][0] = *(const short8*)qrow;
            bq[f][1] = *(const short8*)(qrow + 32);
        }

        // prime tile 0: K async, V reg->transpose (pairs (2m, 2m+1))
        __builtin_amdgcn_global_load_lds((as1p)(kbg + (size_t)sr * D3 + sc),
                                         (as3p)&Ks[0][tid * 8], 16, 0, 0);
        __builtin_amdgcn_global_load_lds((as1p)(kbg + (size_t)(sr + 32) * D3 + sc),
                                         (as3p)&Ks[0][(tid + 256) * 8], 16, 0, 0);
        {
            const unsigned short* vs = vbg + (size_t)(2 * m) * D3 + vo;
            uint4 va = *(const uint4*)vs;
            uint4 vb = *(const uint4*)(vs + (size_t)D3);
            const unsigned short* pa_ = (const unsigned short*)&va;
            const unsigned short* pb_ = (const unsigned short*)&vb;
            #pragma unroll
            for (int j = 0; j < 8; j++)
                Vp[0][(vo + j) * 34 + m] = (unsigned)pa_[j] | ((unsigned)pb_[j] << 16);
        }
        __syncthreads();                       // K0 drained, V0 visible

        f32x4 acc[4][4] = {};                  // [qfrag][d-frag]
        float lsum[4] = {0.f, 0.f, 0.f, 0.f};  // per qfrag, q = lro

        for (int kt = 0; kt < nkt; kt++) {
            const int cur = kt & 1, nxt = cur ^ 1;
            const bool pf = (kt + 1 < nkt);
            uint4 va, vb;
            if (pf) {                          // prefetch kt+1 (overlaps compute)
                const unsigned short* kb1 = kbg + (size_t)((kt + 1) * 64) * D3;
                __builtin_amdgcn_global_load_lds((as1p)(kb1 + (size_t)sr * D3 + sc),
                                                 (as3p)&Ks[nxt][tid * 8], 16, 0, 0);
                __builtin_amdgcn_global_load_lds((as1p)(kb1 + (size_t)(sr + 32) * D3 + sc),
                                                 (as3p)&Ks[nxt][(tid + 256) * 8], 16, 0, 0);
                const unsigned short* vs =
                    vbg + (size_t)((kt + 1) * 64 + 2 * m) * D3 + vo;
                va = *(const uint4*)vs;
                vb = *(const uint4*)(vs + (size_t)D3);
            }

            // S^T = K_slice * Q^T  (swapped operands; pre-scaled so p=exp2(s))
            short8 ak0 = *(const short8*)&Ks[cur][koffA];
            short8 ak1 = *(const short8*)&Ks[cur][koffB];
            f32x4 s0 = {}, s1 = {}, s2 = {}, s3 = {};
            s0 = __builtin_amdgcn_mfma_f32_16x16x32_bf16(ak0, bq[0][0], s0, 0, 0, 0);
            s0 = __builtin_amdgcn_mfma_f32_16x16x32_bf16(ak1, bq[0][1], s0, 0, 0, 0);
            s1 = __builtin_amdgcn_mfma_f32_16x16x32_bf16(ak0, bq[1][0], s1, 0, 0, 0);
            s1 = __builtin_amdgcn_mfma_f32_16x16x32_bf16(ak1, bq[1][1], s1, 0, 0, 0);
            s2 = __builtin_amdgcn_mfma_f32_16x16x32_bf16(ak0, bq[2][0], s2, 0, 0, 0);
            s2 = __builtin_amdgcn_mfma_f32_16x16x32_bf16(ak1, bq[2][1], s2, 0, 0, 0);
            s3 = __builtin_amdgcn_mfma_f32_16x16x32_bf16(ak0, bq[3][0], s3, 0, 0, 0);
            s3 = __builtin_amdgcn_mfma_f32_16x16x32_bf16(ak1, bq[3][1], s3, 0, 0, 0);
            f32x4 sf[4] = {s0, s1, s2, s3};

            const bool dg = (kt == nkt - 1);
            u32x2 pw[4];
            #pragma unroll
            for (int f = 0; f < 4; f++) {
                float v0 = sf[f][0], v1 = sf[f][1], v2 = sf[f][2], v3 = sf[f][3];
                if (dg) {                      // mask k_local(klb+r) > q_local
                    int thr = (f << 4) + lro - klb;
                    if (0 > thr) v0 = -1e30f;
                    if (1 > thr) v1 = -1e30f;
                    if (2 > thr) v2 = -1e30f;
                    if (3 > thr) v3 = -1e30f;
                }
                float p0 = __builtin_amdgcn_exp2f(v0);
                float p1 = __builtin_amdgcn_exp2f(v1);
                float p2 = __builtin_amdgcn_exp2f(v2);
                float p3 = __builtin_amdgcn_exp2f(v3);
                lsum[f] += (p0 + p1) + (p2 + p3);
                unsigned u0, u1;
                asm("v_cvt_pk_bf16_f32 %0, %1, %2" : "=v"(u0) : "v"(p0), "v"(p1));
                asm("v_cvt_pk_bf16_f32 %0, %1, %2" : "=v"(u1) : "v"(p2), "v"(p3));
                pw[f][0] = u0;
                pw[f][1] = u1;
            }

            // V frags: 4 consecutive k at lane's slice, d = nt*16 + lro
            u32x2 vv[4];
            #pragma unroll
            for (int nt = 0; nt < 4; nt++)
                vv[nt] = *(const u32x2*)&Vp[cur][(nt * 16 + lro) * 34 + vcb];

            // O_w += P V  (P direct from registers; 16x16x16 MFMA)
            #pragma unroll
            for (int f = 0; f < 4; f++)
                #pragma unroll
                for (int nt = 0; nt < 4; nt++)
                    asm("v_mfma_f32_16x16x16_bf16 %0, %1, %2, %0"
                        : "+v"(acc[f][nt]) : "v"(pw[f]), "v"(vv[nt]));

            if (pf) {                          // transpose-write V(kt+1)
                const unsigned short* pa_ = (const unsigned short*)&va;
                const unsigned short* pb_ = (const unsigned short*)&vb;
                #pragma unroll
                for (int j = 0; j < 8; j++)
                    Vp[nxt][(vo + j) * 34 + m] = (unsigned)pa_[j] | ((unsigned)pb_[j] << 16);
            }
            __syncthreads();                   // drains async K(kt+1); Vp[nxt] visible
        }

        // ---- epilogue: cross-wave reduce of O and lsum -------------------
        // lsum: reduce across grp lanes (same q, different k-subsets)
        #pragma unroll
        for (int f = 0; f < 4; f++) {
            lsum[f] += __shfl_xor(lsum[f], 16, 64);
            lsum[f] += __shfl_xor(lsum[f], 32, 64);
        }
        if (lane < 16) {
            #pragma unroll
            for (int f = 0; f < 4; f++) Lbuf[wave][f][lro] = lsum[f];
        }

        // O: 4 static rounds; round f: waves != f contribute acc[f] (static
        // index) to RedW[wave]; owner (wave==f) sums, normalizes, stores.
        #pragma unroll
        for (int f = 0; f < 4; f++) {
            __syncthreads();
            if (wave != f) {
                #pragma unroll
                for (int nt = 0; nt < 4; nt++)
                    #pragma unroll
                    for (int r = 0; r < 4; r++)
                        RedW[wave][(grp << 2) + r][nt * 16 + lro] = acc[f][nt][r];
            }
            __syncthreads();
            if (wave == f) {
                #pragma unroll
                for (int w2 = 0; w2 < 4; w2++) {
                    if (w2 == f) continue;     // static skip
                    #pragma unroll
                    for (int nt = 0; nt < 4; nt++)
                        #pragma unroll
                        for (int r = 0; r < 4; r++)
                            acc[f][nt][r] += RedW[w2][(grp << 2) + r][nt * 16 + lro];
                }
                #pragma unroll
                for (int r = 0; r < 4; r++) {
                    int q = (grp << 2) + r;
                    float lt = Lbuf[0][f][q] + Lbuf[1][f][q] +
                               Lbuf[2][f][q] + Lbuf[3][f][q];
                    float inv = 1.0f / lt;
                    int row = q0 + (f << 4) + q;
                    #pragma unroll
                    for (int nt = 0; nt < 4; nt++)
                        Ows[(size_t)(b * S + row) * 1024 + h * 64 + nt * 16 + lro] =
                            f2bf(acc[f][nt][r] * inv);
                }
            }
        }
    }
}

// ---------------------------------------------------------------------------
extern "C" void kernel_launch(void* const* d_in, const int* in_sizes, int n_in,
                              void* d_out, int out_size, void* d_ws, size_t ws_size,
                              hipStream_t stream) {
    const float* x    = (const float*)d_in[0];   // (2, 2048, 1024)
    const int*   pos  = (const int*)d_in[1];     // (2048,)
    const float* Wqkv = (const float*)d_in[2];   // (3072, 1024)
    const float* Wo   = (const float*)d_in[3];   // (1024, 1024)
    float* out = (float*)d_out;                  // (2, 2048, 1024) fp32

    unsigned short* xb    = (unsigned short*)d_ws;            // 4096*1024
    unsigned short* Wqkvb = xb + (size_t)4096 * 1024;         // 3072*1024
    unsigned short* Wob   = Wqkvb + (size_t)3072 * 1024;      // 1024*1024
    unsigned short* qkvb  = Wob + (size_t)1024 * 1024;        // 4096*3072
    unsigned short* Owsb  = qkvb + (size_t)4096 * 3072;       // 4096*1024

    // 0) fp32 -> bf16 (single launch)
    cvt_all_bf16<<<8192, 256, 0, stream>>>(x, Wqkv, Wo, xb, Wqkvb, Wob);

    // 1) QKV projection (M=4096, N=3072, K=1024) + fused RoPE, swizzled LDS
    gemm_nt_mfma<4, 3, true, true><<<768, 256, 0, stream>>>(
        xb, Wqkvb, qkvb, pos, 3072, 1024);

    // 2) causal flash attention (k-sliced waves, swapped QK^T, reg-P)
    flash_attn_mfma<<<dim3(16, 16, 2), 256, 0, stream>>>(qkvb, Owsb);

    // 3) output projection (M=4096, N=1024, K=1024), BM=64, swizzled LDS
    gemm_nt_mfma<2, 1, false, false><<<512, 256, 0, stream>>>(
        Owsb, Wob, out, nullptr, 1024, 1024);
}